// Round 8
// baseline (32.521 us; speedup 1.0000x reference)
//
#include <hip/hip_runtime.h>

// GaussianSpot: out[k,b,i,j] = h/(2*pi*w^2) * exp(-0.5*((i-sx)^2+(j-sy)^2)/w^2)
// Separable: = [scale*exp2(c*(i-sx)^2)] * [exp2(c*(j-sy)^2)],  c = -0.5*log2(e)/w^2
// K=2, B=100000, D=14 -> 200000 spots x 196 px = 39.2M f32 (156.8 MB streamed write).
//
// R7: stage-C DS reduced 8 -> 2 instrs per float4 store.
//  - ey stored REPLICATED (16 floats, ey[t%14]): any f4 slot reads 4 consecutive
//    floats at even offset s = 4q-14i -> two adjacent float2 loads (merge to
//    ds_read2_b64). ex read as {ex[i], ex[i+1]} pair (merge to ds_read2_b32).
//  - Row wrap: s even <= 12, so only s==12 wraps, affecting exactly pixels
//    m=2,3 -> ONE cndmask selects ex[i+1] for e.z/e.w.
//  - Per-spot LDS stride 34 floats (2*sp bank skew, keeps 8B alignment).
// Wave-autonomous barrier-free structure from R6 otherwise unchanged.

typedef float f32x4 __attribute__((ext_vector_type(4)));
typedef float f32x2 __attribute__((ext_vector_type(2)));

#define B_NUM   100000u
#define F_NUM   500
#define D_DIM   14u
#define SPW     16u              // spots per wave
#define WPB     4u               // waves per block (256 threads)
#define SPB     (SPW * WPB)      // 64 spots per block
#define NBLK    (200000 / SPB)   // 3125 blocks exactly
#define SSTRIDE 34u              // per-spot LDS stride (floats): ex[16] + ey[16] + 2 skew
// Per-wave LDS (floats): [0,16) sx | [16,32) sy | [32,48) c | [48,64) scale |
//                        [64 + sp*34 + 0..13] ex | [64 + sp*34 + 16 + 0..15] ey_rep
#define WREG    (64u + SPW * SSTRIDE)   // 608 floats = 2432 B per wave

__global__ __launch_bounds__(256) void gspot_kernel(
    const float* __restrict__ height,
    const float* __restrict__ width,
    const float* __restrict__ xoff,
    const float* __restrict__ yoff,
    const float* __restrict__ tlocs,   // [N, F, 2]
    const int*   __restrict__ n_idx,   // [B]
    const int*   __restrict__ f_idx,   // [B]
    f32x4*       __restrict__ out)
{
    __shared__ float lds[WPB * WREG];

    const float HALF_LOG2E = 0.7213475204444817f;   // 0.5 * log2(e)
    const float INV_2PI    = 0.15915494309189535f;  // 1 / (2*pi)

    const unsigned tid  = threadIdx.x;
    const unsigned wave = tid >> 6;
    const unsigned lane = tid & 63u;
    float* wl = &lds[wave * WREG];
    const unsigned wave_spot0 = blockIdx.x * SPB + wave * SPW;

    // ---- Stage A: 16 lanes resolve the gather chain for this wave's spots ----
    if (lane < SPW) {
        unsigned spot = wave_spot0 + lane;
        unsigned b    = spot >= B_NUM ? spot - B_NUM : spot;   // k*B+b layout, K=2
        float h  = height[spot];
        float w  = width[spot];
        float sx = xoff[spot];
        float sy = yoff[spot];
        int n = n_idx[b];
        int f = f_idx[b];
        const float* tl = tlocs + ((unsigned)(n * F_NUM + f)) * 2u;
        sx += tl[0];
        sy += tl[1];
        float inv = __builtin_amdgcn_rcpf(w * w);
        wl[lane]        = sx;
        wl[16u + lane]  = sy;
        wl[32u + lane]  = -HALF_LOG2E * inv;
        wl[48u + lane]  = h * inv * INV_2PI;
    }
    asm volatile("s_waitcnt lgkmcnt(0)" ::: "memory");
    __builtin_amdgcn_sched_barrier(0);

    // ---- Stage B: per spot: 14 ex + 16 ey_rep = 480 writes, 8 iters x 64 lanes ----
    // r = lane&31 is loop-invariant: r<14 -> ex path; r>=16 -> ey path (t=r-16).
    {
        const unsigned r = lane & 31u;
        #pragma unroll
        for (unsigned k = 0; k < 8u; ++k) {
            unsigned sp = (k << 1) | (lane >> 5);
            unsigned SB = 64u + sp * SSTRIDE;
            float c = wl[32u + sp];
            if (r < D_DIM) {
                float d = (float)r - wl[sp];
                wl[SB + r] = wl[48u + sp] * __builtin_amdgcn_exp2f(c * d * d);
            } else if (r >= 16u) {
                unsigned t = r - 16u;
                unsigned j = t < D_DIM ? t : t - D_DIM;   // replicated wrap
                float d = (float)j - wl[16u + sp];
                wl[SB + 16u + t] = __builtin_amdgcn_exp2f(c * d * d);
            }
        }
    }
    asm volatile("s_waitcnt lgkmcnt(0)" ::: "memory");
    __builtin_amdgcn_sched_barrier(0);

    // ---- Stage C: 784 f4 per wave = 12 full iters + 16 lanes ----
    f32x4* op = out + (size_t)wave_spot0 * 49u;
    #pragma unroll
    for (unsigned k = 0; k < 13u; ++k) {
        unsigned idx = lane + 64u * k;
        if (k < 12u || lane < SPW) {         // 784 = 12*64 + 16
            unsigned sp = idx / 49u;         // magic-mul
            unsigned q  = idx - sp * 49u;
            unsigned p0 = q * 4u;            // first pixel 0..192
            unsigned i  = p0 / D_DIM;        // magic-mul
            unsigned s  = p0 - i * D_DIM;    // even, 0..12
            unsigned SB = 64u + sp * SSTRIDE;

            float ex0 = wl[SB + i];
            float ex1 = wl[SB + i + 1u];     // slot 14 pad read when i=13 (never selected)
            f32x2 eylo = *(const f32x2*)&wl[SB + 16u + s];        // 8B aligned (s even)
            f32x2 eyhi = *(const f32x2*)&wl[SB + 16u + s + 2u];

            float exz = (s == 12u) ? ex1 : ex0;   // only s==12 wraps, pixels m=2,3
            f32x4 e;
            e.x = ex0 * eylo.x;
            e.y = ex0 * eylo.y;
            e.z = exz * eyhi.x;
            e.w = exz * eyhi.y;
            op[idx] = e;
        }
    }
}

extern "C" void kernel_launch(void* const* d_in, const int* in_sizes, int n_in,
                              void* d_out, int out_size, void* d_ws, size_t ws_size,
                              hipStream_t stream) {
    const float* height = (const float*)d_in[0];
    const float* width  = (const float*)d_in[1];
    const float* x      = (const float*)d_in[2];
    const float* y      = (const float*)d_in[3];
    const float* tlocs  = (const float*)d_in[4];
    const int*   n_idx  = (const int*)d_in[5];
    const int*   f_idx  = (const int*)d_in[6];
    f32x4* out = (f32x4*)d_out;

    hipLaunchKernelGGL(gspot_kernel, dim3(NBLK), dim3(256), 0, stream,
                       height, width, x, y, tlocs, n_idx, f_idx, out);
}